// Round 14
// baseline (852.439 us; speedup 1.0000x reference)
//
#include <hip/hip_runtime.h>
#include <math.h>

// Problem constants (fixed by setup_inputs)
#define B_    2
#define L_    4096
#define H_    8
#define D_    64
#define S_    45      // sample_k
#define NT_   45      // n_top
#define BH_   16      // B*H
#define CHV   64      // cumsum chunk length
#define NCHV  64      // L_/CHV
#define KC    128     // attention key-chunk length (per block)
#define SCALE 0.125f  // 1/sqrt(64)
#define NEG_BIG (-1e30f)

// Workspace layout (float element offsets; ints share the same 4B slots).
#define OFF_M     0         // 65536 floats: M[bh][q]
#define OFF_MTOP  65536     // 720 ints:    M_top[bh][u]  (SET semantics; order-free)
#define OFF_T     66304     // 720 floats:  T[bh][u]  (atomic accum)
#define OFF_CTX   67072     // 46080 floats: ctx[bh][u][d] (atomic accum)
#define OFF_VSUM  131072    // 65536 floats: vsum[bh][ch][d]
#define OFF_CNT   196608    // 4 ints: cntM, cntA, cntC (memset to 0 pre-k1)
#define NZERO     46848     // floats zeroed (OFF_T .. OFF_CTX+46080)

typedef __attribute__((ext_vector_type(8))) short s8b;    // 8 bf16 (4 VGPR)
typedef __attribute__((ext_vector_type(4))) float f32x4;  // MFMA accumulator

// DPP row-rotate combine within a 16-lane row (VALU-pipe)
template <int CTRL>
__device__ __forceinline__ float dpp_ror_f(float x) {
    int y = __builtin_amdgcn_update_dpp(0, __float_as_int(x), CTRL, 0xF, 0xF, false);
    return __int_as_float(y);
}
template <int CTRL>
__device__ __forceinline__ int dpp_ror_i(int x) {
    return __builtin_amdgcn_update_dpp(0, x, CTRL, 0xF, 0xF, false);
}

// bf16 <-> f32 bit tricks (bf16 = high 16 bits of fp32; truncation rounding)
__device__ __forceinline__ unsigned f2bf(float x) {
    return (__float_as_uint(x) >> 16);
}
__device__ __forceinline__ float bflo(unsigned u) { return __uint_as_float(u << 16); }
__device__ __forceinline__ float bfhi(unsigned u) { return __uint_as_float(u & 0xffff0000u); }

// monotone fp32 -> uint32 key (order-preserving)
__device__ __forceinline__ unsigned mkey(unsigned u) {
    return (u & 0x80000000u) ? ~u : (u | 0x80000000u);
}

__device__ __forceinline__ int cnt_load(const int* p) {
    return __hip_atomic_load(p, __ATOMIC_ACQUIRE, __HIP_MEMORY_SCOPE_AGENT);
}

// ---------------------------------------------------------------------------
// k1: FUSED  (a) M scores (L2 random-line roofline) + completion signal.
//     (b) V chunk sums. (c) 16 tail blocks: zero T/CTX, SPIN until all 4096
//     M-blocks signal (safe one-way wait: producers never wait; 16 waiters
//     vs ~2048 resident-block capacity -> no deadlock under any schedule),
//     then 4-wave bisection top-45 (16 keys/thread in 4 NAMED uint4 ->
//     register-resident by construction; kills the R11-R13 spill saga).
// ---------------------------------------------------------------------------
__global__ __launch_bounds__(256) void k1(const float* __restrict__ Q,
                                          const float* __restrict__ Kt,
                                          const float* __restrict__ V,
                                          const int* __restrict__ samp,
                                          float* __restrict__ ws)
{
    int tid  = threadIdx.x;
    int w    = tid >> 6;          // 0..3
    int lane = tid & 63;

    __shared__ int soff[4][S_];
    __shared__ int red[2][4];
    __shared__ int wtot[4];

    if (blockIdx.x < 4096) {
        int i   = blockIdx.x;
        int xcd = i & 7;
        int b   = xcd >> 2;
        int hh  = (xcd >> 1) & 1;
        int qq  = ((i >> 3) << 1) | (xcd & 1);   // q-quad index 0..1023

        if (tid < 4 * S_) {
            int qs = tid / S_, ss = tid - qs * S_;
            soff[qs][ss] = (samp[(qq * 4 + qs) * S_ + ss] << 11) | (hh << 10);
        }
        __syncthreads();

        int q  = qq * 4 + w;                     // wave owns one q
        int h4 = lane >> 4;                      // head within half

        const float4 q4 = *(const float4*)(Q +
            ((((long)b * L_ + q) * H_ + hh * 4) << 6) + lane * 4);

        const char* kslab = (const char*)Kt + (long)b * (L_ * 2048);
        unsigned lb = (unsigned)(lane * 16);

        float mx = NEG_BIG, sm = 0.f;
#pragma unroll
        for (int jb = 0; jb < 45; jb += 15) {    // 3 batches x 15 gathers
            float4 kb[15];
#pragma unroll
            for (int j = 0; j < 15; ++j)
                kb[j] = *(const float4*)(kslab +
                        ((unsigned)soff[w][jb + j] + lb));
#pragma unroll
            for (int j = 0; j < 15; ++j) {
                float p = q4.x * kb[j].x + q4.y * kb[j].y +
                          q4.z * kb[j].z + q4.w * kb[j].w;
                p += dpp_ror_f<0x121>(p);   // ror 1
                p += dpp_ror_f<0x122>(p);   // ror 2
                p += dpp_ror_f<0x124>(p);   // ror 4
                p += dpp_ror_f<0x128>(p);   // ror 8 -> 16-lane row sum
                mx = fmaxf(mx, p);
                sm += p;
            }
        }
        if ((lane & 15) == 0)
            ws[OFF_M + ((long)(b * 8 + hh * 4 + h4)) * L_ + q] =
                mx - sm * (1.0f / (float)L_);
        __threadfence();
        __syncthreads();
        if (tid == 0) atomicAdd((int*)ws + OFF_CNT + 0, 1);
    } else if (blockIdx.x < 4352) {
        // V chunk sums: wave per (bh, ch), 16 loads in flight
        int unit = (blockIdx.x - 4096) * 4 + w;   // 0..1023
        int bh = unit >> 6, ch = unit & 63;
        int b = bh >> 3, h = bh & 7;
        const float* vp = V + ((((long)b * L_ + (long)ch * CHV) * H_ + h) << 6) + lane;
        float ssum = 0.f;
#pragma unroll
        for (int ib = 0; ib < CHV; ib += 16) {
            float vb[16];
#pragma unroll
            for (int j = 0; j < 16; ++j) vb[j] = vp[(long)(ib + j) * (H_ * D_)];
#pragma unroll
            for (int j = 0; j < 16; ++j) ssum += vb[j];
        }
        ws[OFF_VSUM + unit * 64 + lane] = ssum;
    } else {
        // ---- tail blocks: zero T/CTX, spin for all M, then top-45 ----
        for (int i = (blockIdx.x - 4352) * 256 + tid; i < NZERO; i += 16 * 256)
            ws[OFF_T + i] = 0.f;

        const int* cnt = (const int*)ws + OFF_CNT;
        while (cnt_load(&cnt[0]) < 4096) __builtin_amdgcn_s_sleep(2);
        __syncthreads();

        int bh = blockIdx.x - 4352;
        // thread owns keys tid*16 .. tid*16+15 in 4 NAMED uint4 registers
        const uint4* m4 = (const uint4*)(ws + OFF_M + (long)bh * L_) + tid * 4;
        uint4 q0 = m4[0], q1 = m4[1], q2 = m4[2], q3 = m4[3];
        q0.x = mkey(q0.x); q0.y = mkey(q0.y); q0.z = mkey(q0.z); q0.w = mkey(q0.w);
        q1.x = mkey(q1.x); q1.y = mkey(q1.y); q1.z = mkey(q1.z); q1.w = mkey(q1.w);
        q2.x = mkey(q2.x); q2.y = mkey(q2.y); q2.z = mkey(q2.z); q2.w = mkey(q2.w);
        q3.x = mkey(q3.x); q3.y = mkey(q3.y); q3.z = mkey(q3.z); q3.w = mkey(q3.w);

        // bisection: largest lam with count(key >= lam) >= 45 (4-wave count)
        unsigned lo = 0u, hi = 0xFFFFFFFFu;
        for (int it = 0; it < 32; ++it) {
            unsigned d = hi - lo;
            unsigned mid = lo + (d >> 1) + (d & 1);   // upper mid, no overflow
            int c16 =
                (q0.x >= mid) + (q0.y >= mid) + (q0.z >= mid) + (q0.w >= mid) +
                (q1.x >= mid) + (q1.y >= mid) + (q1.z >= mid) + (q1.w >= mid) +
                (q2.x >= mid) + (q2.y >= mid) + (q2.z >= mid) + (q2.w >= mid) +
                (q3.x >= mid) + (q3.y >= mid) + (q3.z >= mid) + (q3.w >= mid);
            c16 += dpp_ror_i<0x121>(c16);
            c16 += dpp_ror_i<0x122>(c16);
            c16 += dpp_ror_i<0x124>(c16);
            c16 += dpp_ror_i<0x128>(c16);             // 16-lane row sum
            c16 += __shfl_xor(c16, 16);
            c16 += __shfl_xor(c16, 32);               // wave total
            if (lane == 0) red[it & 1][w] = c16;
            __syncthreads();                          // dbuf: 1 barrier/round
            int tot = red[it & 1][0] + red[it & 1][1] +
                      red[it & 1][2] + red[it & 1][3];
            if (tot >= NT_) lo = mid; else hi = mid - 1;
        }
        unsigned lam = lo;

        // per-thread gt/eq tallies, block-wide packed prefix
        int cgt =
            (q0.x > lam) + (q0.y > lam) + (q0.z > lam) + (q0.w > lam) +
            (q1.x > lam) + (q1.y > lam) + (q1.z > lam) + (q1.w > lam) +
            (q2.x > lam) + (q2.y > lam) + (q2.z > lam) + (q2.w > lam) +
            (q3.x > lam) + (q3.y > lam) + (q3.z > lam) + (q3.w > lam);
        int ceq =
            (q0.x == lam) + (q0.y == lam) + (q0.z == lam) + (q0.w == lam) +
            (q1.x == lam) + (q1.y == lam) + (q1.z == lam) + (q1.w == lam) +
            (q2.x == lam) + (q2.y == lam) + (q2.z == lam) + (q2.w == lam) +
            (q3.x == lam) + (q3.y == lam) + (q3.z == lam) + (q3.w == lam);
        int packed = (cgt << 16) | ceq;               // gt<=44, eq<=4096: no carry
        int incl = packed;
#pragma unroll
        for (int off = 1; off < 64; off <<= 1) {
            int t = __shfl_up(incl, off);
            if (lane >= off) incl += t;
        }
        if (lane == 63) wtot[w] = incl;
        __syncthreads();
        int woff = 0;
#pragma unroll
        for (int w2 = 0; w2 < 4; ++w2) if (w2 < w) woff += wtot[w2];
        int totp = wtot[0] + wtot[1] + wtot[2] + wtot[3];
        int excl = incl - packed + woff;
        int ngt_total = totp >> 16;

        int* Mtop = (int*)ws + OFF_MTOP + bh * NT_;
        int gpos = excl >> 16;
        int epos = ngt_total + (excl & 0xFFFF);
        int base = tid * 16;
#define K2_EMIT1(u, idx)                                                  \
        if ((u) > lam) { Mtop[gpos++] = (idx); }                          \
        else if ((u) == lam) { if (epos < NT_) Mtop[epos] = (idx); ++epos; }
        K2_EMIT1(q0.x, base + 0)  K2_EMIT1(q0.y, base + 1)
        K2_EMIT1(q0.z, base + 2)  K2_EMIT1(q0.w, base + 3)
        K2_EMIT1(q1.x, base + 4)  K2_EMIT1(q1.y, base + 5)
        K2_EMIT1(q1.z, base + 6)  K2_EMIT1(q1.w, base + 7)
        K2_EMIT1(q2.x, base + 8)  K2_EMIT1(q2.y, base + 9)
        K2_EMIT1(q2.z, base + 10) K2_EMIT1(q2.w, base + 11)
        K2_EMIT1(q3.x, base + 12) K2_EMIT1(q3.y, base + 13)
        K2_EMIT1(q3.z, base + 14) K2_EMIT1(q3.w, base + 15)
#undef K2_EMIT1
    }
}

// ---------------------------------------------------------------------------
// k3: FUSED (a) attention (blocks < 1024): R11 chain-diet + MFMA QK^T/PV +
//     atomic CTX/T, + completion signal cntA. (b) cumsum (1024..1279) +
//     signal cntC. (c) kD-waiters (1280..1459): spin until all attn and
//     cumsum blocks signaled (180 waiters vs 1280-block capacity: producers
//     never wait -> deadlock-free under any schedule), then ctx/T + scatter.
// ---------------------------------------------------------------------------
#define KPAD16 72    // bf16 row stride for K tile: 144B
#define PSTR   136   // P16 row stride in shorts: 272B (16B-aligned rows)
__global__ __launch_bounds__(256) void k3(const float* __restrict__ Q,
                                          const float* __restrict__ Kt,
                                          const float* __restrict__ V,
                                          float* __restrict__ out,
                                          float* __restrict__ ws)
{
    __shared__ unsigned short Klds16[KC * KPAD16];  // 18432 B
    __shared__ unsigned short P16[32 * PSTR];       // 8704 B

    int tid = threadIdx.x;
    int* cnt = (int*)ws + OFF_CNT;

    if (blockIdx.x < 1024) {
        int bh = blockIdx.x >> 6;
        int kc = (blockIdx.x >> 1) & 31;
        int ug = blockIdx.x & 1;
        int b = bh >> 3, h = bh & 7;
        int kbase = kc * KC;
        int u0 = ug * 23;
        int NU = ug ? 22 : 23;

        int lane = tid & 63, w = tid >> 6;
        int c = lane & 15, hi = lane >> 4;
        int t = w & 1, Hh = w >> 1;
        int slot = t * 16 + c;                  // q-slot 0..31

        // per-lane selected-q position (L2-hot 180B Mtop row; clamped dup)
        int qp = ((const int*)ws)[OFF_MTOP + bh * NT_ + u0 +
                                  (slot < NU ? slot : NU - 1)];

        // hoisted PV V-loads (latency overlaps the QK section)
        const float* vsrc = V + ((((long)b * L_ + kbase) * H_ + h) << 6)
                              + (w * 16 + c);
        float vf[32];
#pragma unroll
        for (int ks = 0; ks < 4; ++ks)
#pragma unroll
            for (int j = 0; j < 8; ++j)
                vf[ks * 8 + j] = vsrc[(long)(ks * 32 + hi * 8 + j) * (H_ * D_)];

        // direct-global Q fragments: cols hi*8..+7 and 32+hi*8..+7 of Q[qp]
        s8b bq0, bq1;
        {
            const float4* qrow = (const float4*)(Q + ((((long)b * L_ + qp) * H_ + h) << 6));
            float4 qa = qrow[hi * 2], qb = qrow[hi * 2 + 1];
            float4 qc = qrow[8 + hi * 2], qd = qrow[8 + hi * 2 + 1];
            uint4 u0v, u1v;
            u0v.x = (__float_as_uint(qa.x) >> 16) | (__float_as_uint(qa.y) & 0xffff0000u);
            u0v.y = (__float_as_uint(qa.z) >> 16) | (__float_as_uint(qa.w) & 0xffff0000u);
            u0v.z = (__float_as_uint(qb.x) >> 16) | (__float_as_uint(qb.y) & 0xffff0000u);
            u0v.w = (__float_as_uint(qb.z) >> 16) | (__float_as_uint(qb.w) & 0xffff0000u);
            u1v.x = (__float_as_uint(qc.x) >> 16) | (__float_as_uint(qc.y) & 0xffff0000u);
            u1v.y = (__float_as_uint(qc.z) >> 16) | (__float_as_uint(qc.w) & 0xffff0000u);
            u1v.z = (__float_as_uint(qd.x) >> 16) | (__float_as_uint(qd.y) & 0xffff0000u);
            u1v.w = (__float_as_uint(qd.z) >> 16) | (__float_as_uint(qd.w) & 0xffff0000u);
            bq0 = *(s8b*)&u0v;
            bq1 = *(s8b*)&u1v;
        }

        // stage K chunk as bf16, XOR-swizzled (reused by both q-tiles)
        {
            const float4* ksrc4 = (const float4*)(Kt + ((((long)b * L_ + kbase) * H_ + h) << 6));
#pragma unroll
            for (int i = 0; i < 8; ++i) {
                int e = i * 256 + tid;
                int r = e >> 4, c4 = e & 15;
                float4 kv = ksrc4[(long)r * (H_ * D_ / 4) + c4];
                uint2 pk;
                pk.x = (__float_as_uint(kv.x) >> 16) | (__float_as_uint(kv.y) & 0xffff0000u);
                pk.y = (__float_as_uint(kv.z) >> 16) | (__float_as_uint(kv.w) & 0xffff0000u);
                *(uint2*)&Klds16[r * KPAD16 + ((c4 * 4) ^ ((r & 7) << 3))] = pk;
            }
        }
        __syncthreads();

        // MFMA QK^T (swapped) + direct exp (no max; |s|<=~8) + P16 + atomic T
        {
            f32x4 acc0 = {0.f,0.f,0.f,0.f}, acc1 = acc0, acc2 = acc0, acc3 = acc0;
#define QK_TILE(MT, ACC)                                                      \
            {                                                                 \
                int kr = Hh * 64 + (MT) * 16 + c;                             \
                s8b a0 = *(const s8b*)&Klds16[kr * KPAD16 +                   \
                            ((hi * 8) ^ ((kr & 7) << 3))];                    \
                s8b a1 = *(const s8b*)&Klds16[kr * KPAD16 +                   \
                            ((32 + hi * 8) ^ ((kr & 7) << 3))];               \
                ACC = __builtin_amdgcn_mfma_f32_16x16x32_bf16(a0, bq0, ACC, 0, 0, 0); \
                ACC = __builtin_amdgcn_mfma_f32_16x16x32_bf16(a1, bq1, ACC, 0, 0, 0); \
            }
            QK_TILE(0, acc0)
            QK_TILE(1, acc1)
            QK_TILE(2, acc2)
            QK_TILE(3, acc3)
#undef QK_TILE

            float ssum = 0.f;
#pragma unroll
            for (int mt = 0; mt < 4; ++mt) {
                f32x4 a = mt == 0 ? acc0 : (mt == 1 ? acc1 : (mt == 2 ? acc2 : acc3));
                float e[4];
#pragma unroll
                for (int reg = 0; reg < 4; ++reg) {
                    int kpos = kbase + Hh * 64 + mt * 16 + hi * 4 + reg;
                    e[reg] = (kpos > qp) ? 0.f : __expf(a[reg] * SCALE);
                    ssum += e[reg];
                }
                uint2 pk;
                pk.x = f2bf(e[0]) | (f2bf(e[1]) << 16);
                pk.y = f2bf(e[2]) | (f2bf(e[3]) << 16);
                *(uint2*)&P16[slot * PSTR + Hh * 64 + mt * 16 + hi * 4] = pk;
            }
            ssum += __shfl_xor(ssum, 16);
            ssum += __shfl_xor(ssum, 32);       // sum over this 64-key half
            if (hi == 0 && slot < NU)
                atomicAdd(&ws[OFF_T + bh * NT_ + u0 + slot], ssum);
        }
        __syncthreads();

        // MFMA PV from hoisted V registers: ctx[u][d] = P(32x128) x V(128x64)
        {
            f32x4 pacc0 = {0.f,0.f,0.f,0.f}, pacc1 = pacc0;
#pragma unroll
            for (int ks = 0; ks < 4; ++ks) {
                uint4 uv;
                uv.x = (__float_as_uint(vf[ks*8+0]) >> 16) | (__float_as_uint(vf[ks*8+1]) & 0xffff0000u);
                uv.y = (__float_as_uint(vf[ks*8+2]) >> 16) | (__float_as_uint(vf[ks*8+3]) & 0xffff0000u);
                uv.z = (__float_as_uint(vf[ks*8+4]) >> 16) | (__float_as_uint(vf[ks*8+5]) & 0xffff0000u);
                uv.w = (__float_as_uint(vf[ks*8+6]) >> 16) | (__float_as_uint(vf[ks*8+7]) & 0xffff0000u);
                s8b bv = *(s8b*)&uv;
                s8b a0 = *(const s8b*)&P16[(c)      * PSTR + ks * 32 + hi * 8];
                s8b a1 = *(const s8b*)&P16[(16 + c) * PSTR + ks * 32 + hi * 8];
                pacc0 = __builtin_amdgcn_mfma_f32_16x16x32_bf16(a0, bv, pacc0, 0, 0, 0);
                pacc1 = __builtin_amdgcn_mfma_f32_16x16x32_bf16(a1, bv, pacc1, 0, 0, 0);
            }
#pragma unroll
            for (int reg = 0; reg < 4; ++reg) {
                int ua = hi * 4 + reg;
                if (ua < NU)
                    atomicAdd(&ws[OFF_CTX + ((long)(bh * NT_ + u0 + ua) << 6)
                                  + w * 16 + c], pacc0[reg]);
                int ub = 16 + hi * 4 + reg;
                if (ub < NU)
                    atomicAdd(&ws[OFF_CTX + ((long)(bh * NT_ + u0 + ub) << 6)
                                  + w * 16 + c], pacc1[reg]);
            }
        }
        __threadfence();
        __syncthreads();
        if (tid == 0) atomicAdd(&cnt[1], 1);
    } else if (blockIdx.x < 1280) {
        // cumsum write: wave per (bh, ch); prefix from vsum chunk sums
        int w    = tid >> 6;
        int lane = tid & 63;
        int unit = (blockIdx.x - 1024) * 4 + w;  // 0..1023
        int bh = unit >> 6, ch = unit & 63;
        int b = bh >> 3, h = bh & 7;
        int d = lane;

        float acc = 0.f;
        {
            const float* vs = ws + OFF_VSUM + (long)bh * NCHV * 64 + d;
            int c = 0;
            for (; c + 8 <= ch; c += 8) {
                float vb[8];
#pragma unroll
                for (int j = 0; j < 8; ++j) vb[j] = vs[(c + j) * 64];
#pragma unroll
                for (int j = 0; j < 8; ++j) acc += vb[j];
            }
            for (; c < ch; ++c) acc += vs[c * 64];
        }

        const float* vp = V   + ((((long)b * L_ + (long)ch * CHV) * H_ + h) << 6) + d;
        float*       op = out + ((((long)b * L_ + (long)ch * CHV) * H_ + h) << 6) + d;
#pragma unroll
        for (int ib = 0; ib < CHV; ib += 16) {
            float vb[16];
#pragma unroll
            for (int j = 0; j < 16; ++j) vb[j] = vp[(long)(ib + j) * (H_ * D_)];
#pragma unroll
            for (int j = 0; j < 16; ++j) {
                acc += vb[j];
                op[(long)(ib + j) * (H_ * D_)] = acc;
            }
        }
        __threadfence();
        __syncthreads();
        if (tid == 0) atomicAdd(&cnt[2], 1);
    } else {
        // ---- kD waiters: spin for all attn + cumsum blocks, then scatter ----
        while (cnt_load(&cnt[1]) < 1024) __builtin_amdgcn_s_sleep(2);
        while (cnt_load(&cnt[2]) < 256)  __builtin_amdgcn_s_sleep(2);

        int w    = tid >> 6;
        int lane = tid & 63;
        int unit = (blockIdx.x - 1280) * 4 + w;  // 0..719 == bh*45+u
        int bh = unit / NT_;
        int b = bh >> 3, h = bh & 7;

        float T   = ws[OFF_T + unit];
        float ctx = ws[OFF_CTX + ((long)unit << 6) + lane];
        int   qp  = ((const int*)ws)[OFF_MTOP + unit];
        out[((((long)b * L_ + qp) * H_ + h) << 6) + lane] = ctx / T;
    }
}

// ---------------------------------------------------------------------------
extern "C" void kernel_launch(void* const* d_in, const int* in_sizes, int n_in,
                              void* d_out, int out_size, void* d_ws, size_t ws_size,
                              hipStream_t stream)
{
    const float* Q    = (const float*)d_in[0];
    const float* K    = (const float*)d_in[1];
    const float* V    = (const float*)d_in[2];
    const int*   samp = (const int*)d_in[4];   // d_in[3] = attn_mask (unused)
    float* out = (float*)d_out;
    float* ws  = (float*)d_ws;

    // 0: zero the 3 completion counters (16B; stream-ordered, graph-capturable)
    hipMemsetAsync((char*)d_ws + (size_t)OFF_CNT * 4, 0, 16, stream);
    // 1: M scores (4096) + vsum (256) + {zero T/CTX, spin, top-45} (16)
    k1<<<4368, 256, 0, stream>>>(Q, K, V, samp, ws);
    // 2: attn (1024) + cumsum (256) + {spin, ctx/T scatter} (180)
    k3<<<1460, 256, 0, stream>>>(Q, K, V, out, ws);
}

// Round 15
// 152.522 us; speedup vs baseline: 5.5889x; 5.5889x over previous
//
#include <hip/hip_runtime.h>
#include <math.h>

// Problem constants (fixed by setup_inputs)
#define B_    2
#define L_    4096
#define H_    8
#define D_    64
#define S_    45      // sample_k
#define NT_   45      // n_top
#define BH_   16      // B*H
#define CHV   64      // cumsum chunk length
#define NCHV  64      // L_/CHV
#define KC    128     // attention key-chunk length (per block)
#define SCALE 0.125f  // 1/sqrt(64)
#define NEG_BIG (-1e30f)

// Workspace layout (float element offsets; ints share the same 4B slots).
#define OFF_M     0         // 65536 floats: M[bh][q]
#define OFF_MTOP  65536     // 720 ints:    M_top[bh][u]  (SET semantics; order-free)
#define OFF_T     66304     // 720 floats:  T[bh][u]  (atomic accum)
#define OFF_CTX   67072     // 46080 floats: ctx[bh][u][d] (atomic accum)
#define OFF_VSUM  131072    // 65536 floats: vsum[bh][ch][d]
#define NZERO     46848     // floats zeroed (OFF_T .. OFF_CTX+46080)

typedef __attribute__((ext_vector_type(8))) short s8b;    // 8 bf16 (4 VGPR)
typedef __attribute__((ext_vector_type(4))) float f32x4;  // MFMA accumulator

// DPP row-rotate combine within a 16-lane row (VALU-pipe)
template <int CTRL>
__device__ __forceinline__ float dpp_ror_f(float x) {
    int y = __builtin_amdgcn_update_dpp(0, __float_as_int(x), CTRL, 0xF, 0xF, false);
    return __int_as_float(y);
}
template <int CTRL>
__device__ __forceinline__ int dpp_ror_i(int x) {
    return __builtin_amdgcn_update_dpp(0, x, CTRL, 0xF, 0xF, false);
}

// bf16 <-> f32 bit tricks (bf16 = high 16 bits of fp32; truncation rounding)
__device__ __forceinline__ unsigned f2bf(float x) {
    return (__float_as_uint(x) >> 16);
}
__device__ __forceinline__ float bflo(unsigned u) { return __uint_as_float(u << 16); }
__device__ __forceinline__ float bfhi(unsigned u) { return __uint_as_float(u & 0xffff0000u); }

// monotone fp32 -> uint32 key (order-preserving)
__device__ __forceinline__ unsigned mkey(unsigned u) {
    return (u & 0x80000000u) ? ~u : (u | 0x80000000u);
}

// ---------------------------------------------------------------------------
// k1: FUSED  (a) M scores (per-XCD L2 random-line roofline; fp16 screen and
//     SW pipelining both refuted R1/R2). (b) V chunk sums. (c) 16 tail
//     blocks: zero T/CTX accumulators. NO fences/spins (R14 lesson: device
//     -scope fences per block thrash non-coherent XCD L2s; cross-XCD
//     publication only at kernel boundaries).
// ---------------------------------------------------------------------------
__global__ __launch_bounds__(256) void k1(const float* __restrict__ Q,
                                          const float* __restrict__ Kt,
                                          const float* __restrict__ V,
                                          const int* __restrict__ samp,
                                          float* __restrict__ ws)
{
    int tid  = threadIdx.x;
    int w    = tid >> 6;          // 0..3
    int lane = tid & 63;

    if (blockIdx.x < 4096) {
        int i   = blockIdx.x;
        int xcd = i & 7;
        int b   = xcd >> 2;
        int hh  = (xcd >> 1) & 1;
        int qq  = ((i >> 3) << 1) | (xcd & 1);   // q-quad index 0..1023

        __shared__ int soff[4][S_];              // byte offsets idx*2048 | hh*1024
        if (tid < 4 * S_) {
            int qs = tid / S_, ss = tid - qs * S_;
            soff[qs][ss] = (samp[(qq * 4 + qs) * S_ + ss] << 11) | (hh << 10);
        }
        __syncthreads();

        int q  = qq * 4 + w;                     // wave owns one q
        int h4 = lane >> 4;                      // head within half

        const float4 q4 = *(const float4*)(Q +
            ((((long)b * L_ + q) * H_ + hh * 4) << 6) + lane * 4);

        const char* kslab = (const char*)Kt + (long)b * (L_ * 2048);
        unsigned lb = (unsigned)(lane * 16);

        float mx = NEG_BIG, sm = 0.f;
#pragma unroll
        for (int jb = 0; jb < 45; jb += 15) {    // 3 batches x 15 gathers
            float4 kb[15];
#pragma unroll
            for (int j = 0; j < 15; ++j)
                kb[j] = *(const float4*)(kslab +
                        ((unsigned)soff[w][jb + j] + lb));
#pragma unroll
            for (int j = 0; j < 15; ++j) {
                float p = q4.x * kb[j].x + q4.y * kb[j].y +
                          q4.z * kb[j].z + q4.w * kb[j].w;
                p += dpp_ror_f<0x121>(p);   // ror 1
                p += dpp_ror_f<0x122>(p);   // ror 2
                p += dpp_ror_f<0x124>(p);   // ror 4
                p += dpp_ror_f<0x128>(p);   // ror 8 -> 16-lane row sum
                mx = fmaxf(mx, p);
                sm += p;
            }
        }
        if ((lane & 15) == 0)
            ws[OFF_M + ((long)(b * 8 + hh * 4 + h4)) * L_ + q] =
                mx - sm * (1.0f / (float)L_);
    } else if (blockIdx.x < 4352) {
        // V chunk sums: wave per (bh, ch), 16 loads in flight
        int unit = (blockIdx.x - 4096) * 4 + w;   // 0..1023
        int bh = unit >> 6, ch = unit & 63;
        int b = bh >> 3, h = bh & 7;
        const float* vp = V + ((((long)b * L_ + (long)ch * CHV) * H_ + h) << 6) + lane;
        float ssum = 0.f;
#pragma unroll
        for (int ib = 0; ib < CHV; ib += 16) {
            float vb[16];
#pragma unroll
            for (int j = 0; j < 16; ++j) vb[j] = vp[(long)(ib + j) * (H_ * D_)];
#pragma unroll
            for (int j = 0; j < 16; ++j) ssum += vb[j];
        }
        ws[OFF_VSUM + unit * 64 + lane] = ssum;
    } else {
        // zero T + CTX atomic accumulators (46848 floats over 16x256 threads)
        for (int i = (blockIdx.x - 4352) * 256 + tid; i < NZERO; i += 16 * 256)
            ws[OFF_T + i] = 0.f;
    }
}

// ---------------------------------------------------------------------------
// k2c: FUSED  (a) top-45 per (b,h): blocks 0..15, 4-wave register-resident
//     bisection (16 keys/thread in 4 NAMED uint4 -> no SROA spill; R14's
//     verified logic). (b) cumsum write: blocks 16..271. Both depend only on
//     k1 -> run concurrently; previously cumsum ran serialized in k3's tail
//     (dispatched after 1024 attn blocks at ~full residency) while top-45
//     ran alone on 16 blocks. Pairing them fills both gaps.
// ---------------------------------------------------------------------------
__global__ __launch_bounds__(256) void k2c(const float* __restrict__ V,
                                           float* __restrict__ out,
                                           float* __restrict__ ws)
{
    int tid  = threadIdx.x;
    int w    = tid >> 6;
    int lane = tid & 63;

    if (blockIdx.x < 16) {
        __shared__ int red[2][4];
        __shared__ int wtot[4];

        int bh = blockIdx.x;
        // thread owns keys tid*16 .. tid*16+15 in 4 NAMED uint4 registers
        const uint4* m4 = (const uint4*)(ws + OFF_M + (long)bh * L_) + tid * 4;
        uint4 q0 = m4[0], q1 = m4[1], q2 = m4[2], q3 = m4[3];
        q0.x = mkey(q0.x); q0.y = mkey(q0.y); q0.z = mkey(q0.z); q0.w = mkey(q0.w);
        q1.x = mkey(q1.x); q1.y = mkey(q1.y); q1.z = mkey(q1.z); q1.w = mkey(q1.w);
        q2.x = mkey(q2.x); q2.y = mkey(q2.y); q2.z = mkey(q2.z); q2.w = mkey(q2.w);
        q3.x = mkey(q3.x); q3.y = mkey(q3.y); q3.z = mkey(q3.z); q3.w = mkey(q3.w);

        // bisection: largest lam with count(key >= lam) >= 45 (4-wave count)
        unsigned lo = 0u, hi = 0xFFFFFFFFu;
        for (int it = 0; it < 32; ++it) {
            unsigned d = hi - lo;
            unsigned mid = lo + (d >> 1) + (d & 1);   // upper mid, no overflow
            int c16 =
                (q0.x >= mid) + (q0.y >= mid) + (q0.z >= mid) + (q0.w >= mid) +
                (q1.x >= mid) + (q1.y >= mid) + (q1.z >= mid) + (q1.w >= mid) +
                (q2.x >= mid) + (q2.y >= mid) + (q2.z >= mid) + (q2.w >= mid) +
                (q3.x >= mid) + (q3.y >= mid) + (q3.z >= mid) + (q3.w >= mid);
            c16 += dpp_ror_i<0x121>(c16);
            c16 += dpp_ror_i<0x122>(c16);
            c16 += dpp_ror_i<0x124>(c16);
            c16 += dpp_ror_i<0x128>(c16);             // 16-lane row sum
            c16 += __shfl_xor(c16, 16);
            c16 += __shfl_xor(c16, 32);               // wave total
            if (lane == 0) red[it & 1][w] = c16;
            __syncthreads();                          // dbuf: 1 barrier/round
            int tot = red[it & 1][0] + red[it & 1][1] +
                      red[it & 1][2] + red[it & 1][3];
            if (tot >= NT_) lo = mid; else hi = mid - 1;
        }
        unsigned lam = lo;

        // per-thread gt/eq tallies, block-wide packed prefix
        int cgt =
            (q0.x > lam) + (q0.y > lam) + (q0.z > lam) + (q0.w > lam) +
            (q1.x > lam) + (q1.y > lam) + (q1.z > lam) + (q1.w > lam) +
            (q2.x > lam) + (q2.y > lam) + (q2.z > lam) + (q2.w > lam) +
            (q3.x > lam) + (q3.y > lam) + (q3.z > lam) + (q3.w > lam);
        int ceq =
            (q0.x == lam) + (q0.y == lam) + (q0.z == lam) + (q0.w == lam) +
            (q1.x == lam) + (q1.y == lam) + (q1.z == lam) + (q1.w == lam) +
            (q2.x == lam) + (q2.y == lam) + (q2.z == lam) + (q2.w == lam) +
            (q3.x == lam) + (q3.y == lam) + (q3.z == lam) + (q3.w == lam);
        int packed = (cgt << 16) | ceq;               // gt<=44, eq<=4096: no carry
        int incl = packed;
#pragma unroll
        for (int off = 1; off < 64; off <<= 1) {
            int t = __shfl_up(incl, off);
            if (lane >= off) incl += t;
        }
        if (lane == 63) wtot[w] = incl;
        __syncthreads();
        int woff = 0;
#pragma unroll
        for (int w2 = 0; w2 < 4; ++w2) if (w2 < w) woff += wtot[w2];
        int totp = wtot[0] + wtot[1] + wtot[2] + wtot[3];
        int excl = incl - packed + woff;
        int ngt_total = totp >> 16;

        int* Mtop = (int*)ws + OFF_MTOP + bh * NT_;
        int gpos = excl >> 16;
        int epos = ngt_total + (excl & 0xFFFF);
        int base = tid * 16;
#define K2_EMIT1(u, idx)                                                  \
        if ((u) > lam) { Mtop[gpos++] = (idx); }                          \
        else if ((u) == lam) { if (epos < NT_) Mtop[epos] = (idx); ++epos; }
        K2_EMIT1(q0.x, base + 0)  K2_EMIT1(q0.y, base + 1)
        K2_EMIT1(q0.z, base + 2)  K2_EMIT1(q0.w, base + 3)
        K2_EMIT1(q1.x, base + 4)  K2_EMIT1(q1.y, base + 5)
        K2_EMIT1(q1.z, base + 6)  K2_EMIT1(q1.w, base + 7)
        K2_EMIT1(q2.x, base + 8)  K2_EMIT1(q2.y, base + 9)
        K2_EMIT1(q2.z, base + 10) K2_EMIT1(q2.w, base + 11)
        K2_EMIT1(q3.x, base + 12) K2_EMIT1(q3.y, base + 13)
        K2_EMIT1(q3.z, base + 14) K2_EMIT1(q3.w, base + 15)
#undef K2_EMIT1
    } else {
        // cumsum write: wave per (bh, ch); prefix from vsum chunk sums
        int unit = (blockIdx.x - 16) * 4 + w;    // 0..1023
        int bh = unit >> 6, ch = unit & 63;
        int b = bh >> 3, h = bh & 7;
        int d = lane;

        float acc = 0.f;
        {
            const float* vs = ws + OFF_VSUM + (long)bh * NCHV * 64 + d;
            int c = 0;
            for (; c + 8 <= ch; c += 8) {
                float vb[8];
#pragma unroll
                for (int j = 0; j < 8; ++j) vb[j] = vs[(c + j) * 64];
#pragma unroll
                for (int j = 0; j < 8; ++j) acc += vb[j];
            }
            for (; c < ch; ++c) acc += vs[c * 64];
        }

        const float* vp = V   + ((((long)b * L_ + (long)ch * CHV) * H_ + h) << 6) + d;
        float*       op = out + ((((long)b * L_ + (long)ch * CHV) * H_ + h) << 6) + d;
#pragma unroll
        for (int ib = 0; ib < CHV; ib += 16) {
            float vb[16];
#pragma unroll
            for (int j = 0; j < 16; ++j) vb[j] = vp[(long)(ib + j) * (H_ * D_)];
#pragma unroll
            for (int j = 0; j < 16; ++j) {
                acc += vb[j];
                op[(long)(ib + j) * (H_ * D_)] = acc;
            }
        }
    }
}

// ---------------------------------------------------------------------------
// k3: attention ONLY (1024 blocks; fully co-resident at ~4-5 blocks/CU).
//     R11 chain-diet: per-lane Mtop read, direct-global Q fragments, V loads
//     hoisted above QK, 2 barriers, LDS 27.3 KB. MFMA QK^T (swapped) +
//     direct exp (no max; |s|<=~8 fp32-safe) + MFMA PV + atomic CTX/T.
// ---------------------------------------------------------------------------
#define KPAD16 72    // bf16 row stride for K tile: 144B
#define PSTR   136   // P16 row stride in shorts: 272B (16B-aligned rows)
__global__ __launch_bounds__(256) void k3(const float* __restrict__ Q,
                                          const float* __restrict__ Kt,
                                          const float* __restrict__ V,
                                          float* __restrict__ ws)
{
    __shared__ unsigned short Klds16[KC * KPAD16];  // 18432 B
    __shared__ unsigned short P16[32 * PSTR];       // 8704 B

    int tid = threadIdx.x;

    int bh = blockIdx.x >> 6;
    int kc = (blockIdx.x >> 1) & 31;
    int ug = blockIdx.x & 1;
    int b = bh >> 3, h = bh & 7;
    int kbase = kc * KC;
    int u0 = ug * 23;
    int NU = ug ? 22 : 23;

    int lane = tid & 63, w = tid >> 6;
    int c = lane & 15, hi = lane >> 4;
    int t = w & 1, Hh = w >> 1;
    int slot = t * 16 + c;                  // q-slot 0..31

    // per-lane selected-q position (L2-hot 180B Mtop row; clamped dup)
    int qp = ((const int*)ws)[OFF_MTOP + bh * NT_ + u0 +
                              (slot < NU ? slot : NU - 1)];

    // hoisted PV V-loads (latency overlaps the QK section)
    const float* vsrc = V + ((((long)b * L_ + kbase) * H_ + h) << 6)
                          + (w * 16 + c);
    float vf[32];
#pragma unroll
    for (int ks = 0; ks < 4; ++ks)
#pragma unroll
        for (int j = 0; j < 8; ++j)
            vf[ks * 8 + j] = vsrc[(long)(ks * 32 + hi * 8 + j) * (H_ * D_)];

    // direct-global Q fragments: cols hi*8..+7 and 32+hi*8..+7 of Q[qp]
    s8b bq0, bq1;
    {
        const float4* qrow = (const float4*)(Q + ((((long)b * L_ + qp) * H_ + h) << 6));
        float4 qa = qrow[hi * 2], qb = qrow[hi * 2 + 1];
        float4 qc = qrow[8 + hi * 2], qd = qrow[8 + hi * 2 + 1];
        uint4 u0v, u1v;
        u0v.x = (__float_as_uint(qa.x) >> 16) | (__float_as_uint(qa.y) & 0xffff0000u);
        u0v.y = (__float_as_uint(qa.z) >> 16) | (__float_as_uint(qa.w) & 0xffff0000u);
        u0v.z = (__float_as_uint(qb.x) >> 16) | (__float_as_uint(qb.y) & 0xffff0000u);
        u0v.w = (__float_as_uint(qb.z) >> 16) | (__float_as_uint(qb.w) & 0xffff0000u);
        u1v.x = (__float_as_uint(qc.x) >> 16) | (__float_as_uint(qc.y) & 0xffff0000u);
        u1v.y = (__float_as_uint(qc.z) >> 16) | (__float_as_uint(qc.w) & 0xffff0000u);
        u1v.z = (__float_as_uint(qd.x) >> 16) | (__float_as_uint(qd.y) & 0xffff0000u);
        u1v.w = (__float_as_uint(qd.z) >> 16) | (__float_as_uint(qd.w) & 0xffff0000u);
        bq0 = *(s8b*)&u0v;
        bq1 = *(s8b*)&u1v;
    }

    // stage K chunk as bf16, XOR-swizzled (reused by both q-tiles)
    {
        const float4* ksrc4 = (const float4*)(Kt + ((((long)b * L_ + kbase) * H_ + h) << 6));
#pragma unroll
        for (int i = 0; i < 8; ++i) {
            int e = i * 256 + tid;
            int r = e >> 4, c4 = e & 15;
            float4 kv = ksrc4[(long)r * (H_ * D_ / 4) + c4];
            uint2 pk;
            pk.x = (__float_as_uint(kv.x) >> 16) | (__float_as_uint(kv.y) & 0xffff0000u);
            pk.y = (__float_as_uint(kv.z) >> 16) | (__float_as_uint(kv.w) & 0xffff0000u);
            *(uint2*)&Klds16[r * KPAD16 + ((c4 * 4) ^ ((r & 7) << 3))] = pk;
        }
    }
    __syncthreads();

    // MFMA QK^T (swapped) + direct exp (no max; |s|<=~8) + P16 + atomic T
    {
        f32x4 acc0 = {0.f,0.f,0.f,0.f}, acc1 = acc0, acc2 = acc0, acc3 = acc0;
#define QK_TILE(MT, ACC)                                                      \
        {                                                                     \
            int kr = Hh * 64 + (MT) * 16 + c;                                 \
            s8b a0 = *(const s8b*)&Klds16[kr * KPAD16 +                       \
                        ((hi * 8) ^ ((kr & 7) << 3))];                        \
            s8b a1 = *(const s8b*)&Klds16[kr * KPAD16 +                       \
                        ((32 + hi * 8) ^ ((kr & 7) << 3))];                   \
            ACC = __builtin_amdgcn_mfma_f32_16x16x32_bf16(a0, bq0, ACC, 0, 0, 0); \
            ACC = __builtin_amdgcn_mfma_f32_16x16x32_bf16(a1, bq1, ACC, 0, 0, 0); \
        }
        QK_TILE(0, acc0)
        QK_TILE(1, acc1)
        QK_TILE(2, acc2)
        QK_TILE(3, acc3)
#undef QK_TILE

        float ssum = 0.f;
#pragma unroll
        for (int mt = 0; mt < 4; ++mt) {
            f32x4 a = mt == 0 ? acc0 : (mt == 1 ? acc1 : (mt == 2 ? acc2 : acc3));
            float e[4];
#pragma unroll
            for (int reg = 0; reg < 4; ++reg) {
                int kpos = kbase + Hh * 64 + mt * 16 + hi * 4 + reg;
                e[reg] = (kpos > qp) ? 0.f : __expf(a[reg] * SCALE);
                ssum += e[reg];
            }
            uint2 pk;
            pk.x = f2bf(e[0]) | (f2bf(e[1]) << 16);
            pk.y = f2bf(e[2]) | (f2bf(e[3]) << 16);
            *(uint2*)&P16[slot * PSTR + Hh * 64 + mt * 16 + hi * 4] = pk;
        }
        ssum += __shfl_xor(ssum, 16);
        ssum += __shfl_xor(ssum, 32);       // sum over this 64-key half
        if (hi == 0 && slot < NU)
            atomicAdd(&ws[OFF_T + bh * NT_ + u0 + slot], ssum);
    }
    __syncthreads();

    // MFMA PV from hoisted V registers: ctx[u][d] = P(32x128) x V(128x64)
    {
        f32x4 pacc0 = {0.f,0.f,0.f,0.f}, pacc1 = pacc0;
#pragma unroll
        for (int ks = 0; ks < 4; ++ks) {
            uint4 uv;
            uv.x = (__float_as_uint(vf[ks*8+0]) >> 16) | (__float_as_uint(vf[ks*8+1]) & 0xffff0000u);
            uv.y = (__float_as_uint(vf[ks*8+2]) >> 16) | (__float_as_uint(vf[ks*8+3]) & 0xffff0000u);
            uv.z = (__float_as_uint(vf[ks*8+4]) >> 16) | (__float_as_uint(vf[ks*8+5]) & 0xffff0000u);
            uv.w = (__float_as_uint(vf[ks*8+6]) >> 16) | (__float_as_uint(vf[ks*8+7]) & 0xffff0000u);
            s8b bv = *(s8b*)&uv;
            s8b a0 = *(const s8b*)&P16[(c)      * PSTR + ks * 32 + hi * 8];
            s8b a1 = *(const s8b*)&P16[(16 + c) * PSTR + ks * 32 + hi * 8];
            pacc0 = __builtin_amdgcn_mfma_f32_16x16x32_bf16(a0, bv, pacc0, 0, 0, 0);
            pacc1 = __builtin_amdgcn_mfma_f32_16x16x32_bf16(a1, bv, pacc1, 0, 0, 0);
        }
#pragma unroll
        for (int reg = 0; reg < 4; ++reg) {
            int ua = hi * 4 + reg;
            if (ua < NU)
                atomicAdd(&ws[OFF_CTX + ((long)(bh * NT_ + u0 + ua) << 6)
                              + w * 16 + c], pacc0[reg]);
            int ub = 16 + hi * 4 + reg;
            if (ub < NU)
                atomicAdd(&ws[OFF_CTX + ((long)(bh * NT_ + u0 + ub) << 6)
                              + w * 16 + c], pacc1[reg]);
        }
    }
}

// ---------------------------------------------------------------------------
// kD: ctx/T + scatter. 180 blocks x 4 waves; wave = one (bh,u) unit.
// ---------------------------------------------------------------------------
__global__ __launch_bounds__(256) void kD(float* __restrict__ out,
                                          const float* __restrict__ ws)
{
    int tid  = threadIdx.x;
    int w    = tid >> 6;
    int lane = tid & 63;
    int unit = blockIdx.x * 4 + w;              // 0..719 == bh*45+u
    int bh = unit / NT_;
    int b = bh >> 3, h = bh & 7;

    float T   = ws[OFF_T + unit];
    float ctx = ws[OFF_CTX + ((long)unit << 6) + lane];
    int   qp  = ((const int*)ws)[OFF_MTOP + unit];
    out[((((long)b * L_ + qp) * H_ + h) << 6) + lane] = ctx / T;
}

// ---------------------------------------------------------------------------
extern "C" void kernel_launch(void* const* d_in, const int* in_sizes, int n_in,
                              void* d_out, int out_size, void* d_ws, size_t ws_size,
                              hipStream_t stream)
{
    const float* Q    = (const float*)d_in[0];
    const float* K    = (const float*)d_in[1];
    const float* V    = (const float*)d_in[2];
    const int*   samp = (const int*)d_in[4];   // d_in[3] = attn_mask (unused)
    float* out = (float*)d_out;
    float* ws  = (float*)d_ws;

    // 1: M scores (4096) + V chunk sums (256) + T/CTX zeroing (16)
    k1<<<4368, 256, 0, stream>>>(Q, K, V, samp, ws);
    // 2: top-45 (16 blocks, register bisection) || cumsum write (256 blocks)
    k2c<<<272, 256, 0, stream>>>(V, out, ws);
    // 3: attention only (1024 blocks, fully co-resident)
    k3<<<1024, 256, 0, stream>>>(Q, K, V, ws);
    // 4: ctx/T + scatter (180 x 256; wave = one unit)
    kD<<<180, 256, 0, stream>>>(out, ws);
}